// Round 1
// baseline (126.070 us; speedup 1.0000x reference)
//
#include <hip/hip_runtime.h>

#define HGT 128
#define WID 128
#define HW  (HGT*WID)        // 16384
#define CIN 64
#define NPIX (4*HW)          // 65536 pixels total
#define TS 16                // pass2 tile side
#define HS 24                // halo side (TS + 2*4)
#define HPX (HS*HS)          // 576

// ---------------------------------------------------------------------------
// Pass 1: per-pixel 1x1 convs f1/f2 (16 ch each), |f2|^2, bilinear upsample.
// Weights staged in LDS transposed [c][32], wave-uniform reads -> broadcast.
// unroll 8 on the channel loop: 8 independent global loads in flight per
// wait (was 4) -> halves the number of latency exposures at 1 wave/SIMD.
// ---------------------------------------------------------------------------
__global__ __launch_bounds__(256) void pass1_kernel(
    const float* __restrict__ delta, const float* __restrict__ outlo,
    const float* __restrict__ w1, const float* __restrict__ b1,
    const float* __restrict__ w2, const float* __restrict__ b2,
    float4* __restrict__ f1p, float4* __restrict__ f2p, float4* __restrict__ rec)
{
    __shared__ float wlds[64][32];   // [c][o]; o<16 -> w1[o], o>=16 -> w2[o-16]
    {
        const int t = threadIdx.x;
#pragma unroll
        for (int s = 0; s < 8; ++s) {
            const int idx = t + s * 256;          // 0..2047
            const int c = idx >> 5, o = idx & 31;
            wlds[c][o] = (o < 16) ? w1[o * 64 + c] : w2[(o - 16) * 64 + c];
        }
    }
    __syncthreads();

    const int g = blockIdx.x * 256 + threadIdx.x;   // 0..65535
    const int n = g >> 14;
    const int p = g & (HW - 1);

    float f1a[16], f2a[16];
#pragma unroll
    for (int o = 0; o < 16; ++o) { f1a[o] = b1[o]; f2a[o] = b2[o]; }

    const float* dbase = delta + n * CIN * HW + p;
#pragma unroll 8
    for (int c = 0; c < CIN; ++c) {
        const float d = dbase[c * HW];
        const float4* wr = (const float4*)(&wlds[c][0]);  // uniform -> broadcast
#pragma unroll
        for (int k = 0; k < 4; ++k) {
            const float4 wv = wr[k];
            f1a[4*k+0] = fmaf(wv.x, d, f1a[4*k+0]);
            f1a[4*k+1] = fmaf(wv.y, d, f1a[4*k+1]);
            f1a[4*k+2] = fmaf(wv.z, d, f1a[4*k+2]);
            f1a[4*k+3] = fmaf(wv.w, d, f1a[4*k+3]);
        }
#pragma unroll
        for (int k = 0; k < 4; ++k) {
            const float4 wv = wr[4 + k];
            f2a[4*k+0] = fmaf(wv.x, d, f2a[4*k+0]);
            f2a[4*k+1] = fmaf(wv.y, d, f2a[4*k+1]);
            f2a[4*k+2] = fmaf(wv.z, d, f2a[4*k+2]);
            f2a[4*k+3] = fmaf(wv.w, d, f2a[4*k+3]);
        }
    }

    float f2sq = 0.f;
#pragma unroll
    for (int o = 0; o < 16; ++o) f2sq = fmaf(f2a[o], f2a[o], f2sq);

#pragma unroll
    for (int k = 0; k < 4; ++k) {
        f1p[k * NPIX + g] = make_float4(f1a[4*k], f1a[4*k+1], f1a[4*k+2], f1a[4*k+3]);
        f2p[k * NPIX + g] = make_float4(f2a[4*k], f2a[4*k+1], f2a[4*k+2], f2a[4*k+3]);
    }

    // bilinear align_corners upsample of out [N,2,64,64] at (y,x)
    const int y = p >> 7, x = p & 127;
    const float ys = (float)(y * 63) / 127.0f;
    const float xs = (float)(x * 63) / 127.0f;
    const int iy0 = (int)ys, ix0 = (int)xs;
    const float fy = ys - (float)iy0, fx = xs - (float)ix0;
    const int iy1 = min(iy0 + 1, 63), ix1 = min(ix0 + 1, 63);
    const float* ob = outlo + n * 2 * 4096;
    float o01[2];
#pragma unroll
    for (int cc = 0; cc < 2; ++cc) {
        const float* oc = ob + cc * 4096;
        const float v00 = oc[iy0*64+ix0], v01 = oc[iy0*64+ix1];
        const float v10 = oc[iy1*64+ix0], v11 = oc[iy1*64+ix1];
        const float top = v00 + fx * (v01 - v00);
        const float bot = v10 + fx * (v11 - v10);
        o01[cc] = top + fy * (bot - top);
    }
    rec[g] = make_float4(o01[0], o01[1], f2sq, 0.f);
}

// 16-FMA dot of a register f1 fragment against one halo pixel's 4 f2 planes.
#define DOT16(fr, A, B, C, D, out)                                             \
    {                                                                          \
        float d0 = fr[0]*A.x, d1 = fr[1]*A.y, d2 = fr[2]*A.z, d3 = fr[3]*A.w;  \
        d0 = fmaf(fr[ 4], B.x, d0); d1 = fmaf(fr[ 5], B.y, d1);                \
        d2 = fmaf(fr[ 6], B.z, d2); d3 = fmaf(fr[ 7], B.w, d3);                \
        d0 = fmaf(fr[ 8], C.x, d0); d1 = fmaf(fr[ 9], C.y, d1);                \
        d2 = fmaf(fr[10], C.z, d2); d3 = fmaf(fr[11], C.w, d3);                \
        d0 = fmaf(fr[12], D.x, d0); d1 = fmaf(fr[13], D.y, d1);                \
        d2 = fmaf(fr[14], D.z, d2); d3 = fmaf(fr[15], D.w, d3);                \
        out = (d0 + d1) + (d2 + d3);                                           \
    }

// ---------------------------------------------------------------------------
// Pass 2: split-tap x2-vertical coarsening.
// Each thread t (and its partner t+128) owns the SAME vertical pixel pair
// (rows 2*ty2, 2*ty2+1 of the 16x16 tile). The pair's windows span 10 halo
// rows; wave-half 0 (t<128) processes rows ii=0..4, wave-half 1 rows 5..9.
// Each (ii,j) tap's 5 float4 LDS reads are shared by BOTH pixels' dots ->
// ds_read_b128 per CU drops 1620 -> 900 (-44%), the pass2 bottleneck.
// Partial (sum_w, sum_w*r0, sum_w*r1) merged through 3 KB LDS (sums of exp
// are linear; no max-shift used, same numerics as before). All row-validity
// predicates (ii<9 / ii>0) are wave-uniform -> s_cbranch, no divergence.
// Occupancy unchanged: 256 thr, 4 waves/CU, 1 block/CU, 49152 B LDS.
// ---------------------------------------------------------------------------
__global__ __launch_bounds__(256, 1) void pass2_kernel(
    const float4* __restrict__ f1p, const float4* __restrict__ f2p,
    const float4* __restrict__ rec, const float* __restrict__ ab,
    const float* __restrict__ gdp, const float* __restrict__ gsp,
    float* __restrict__ outp)
{
    __shared__ float4 sf[5][HPX];     // 46080 B: 4 f2 planes + (r0,r1,f2sq)
    __shared__ float part[6][128];    // 3072 B: half-1 partials

    const int t = threadIdx.x;
    const int n = blockIdx.z;
    const int bx = blockIdx.x * TS, by = blockIdx.y * TS;

    // ---- fill halo ----
#pragma unroll
    for (int s = 0; s < 3; ++s) {
        const int px = t + s * 256;
        if (px < HPX) {
            const int hy = px / 24, hx = px - hy * 24;
            int gy = by - 4 + hy; gy = gy < 0 ? -gy : (gy > 127 ? 254 - gy : gy);
            int gx = bx - 4 + hx; gx = gx < 0 ? -gx : (gx > 127 ? 254 - gx : gx);
            const int gp = n * HW + gy * 128 + gx;
            sf[0][px] = f2p[0 * NPIX + gp];
            sf[1][px] = f2p[1 * NPIX + gp];
            sf[2][px] = f2p[2 * NPIX + gp];
            sf[3][px] = f2p[3 * NPIX + gp];
            sf[4][px] = rec[gp];
        }
    }
    __syncthreads();

    const float gd = gdp[0], gs = gsp[0];
    const int tx   = t & 15;
    const int ty2  = (t >> 4) & 7;    // row pair 0..7
    const int half = t >> 7;          // 0: tap rows ii=0..4, 1: ii=5..9
    const int y0 = ty2 * 2;
    const int p0 = (by + y0) * 128 + (bx + tx);   // lower pixel; p1 = p0+128
    const int g0 = n * HW + p0;

    float f1r0[16], f1r1[16];
#pragma unroll
    for (int k = 0; k < 4; ++k) {
        const float4 v0 = f1p[k * NPIX + g0];
        f1r0[4*k] = v0.x; f1r0[4*k+1] = v0.y; f1r0[4*k+2] = v0.z; f1r0[4*k+3] = v0.w;
        const float4 v1 = f1p[k * NPIX + g0 + 128];
        f1r1[4*k] = v1.x; f1r1[4*k+1] = v1.y; f1r1[4*k+2] = v1.z; f1r1[4*k+3] = v1.w;
    }
    float f1sq0 = 0.f, f1sq1 = 0.f;
#pragma unroll
    for (int o = 0; o < 16; ++o) {
        f1sq0 = fmaf(f1r0[o], f1r0[o], f1sq0);
        f1sq1 = fmaf(f1r1[o], f1r1[o], f1sq1);
    }
    const float c00 = -gd * f1sq0, c01 = -gd * f1sq1;
    const float gd2 = 2.0f * gd;

    float s0 = 0.f, a00 = 0.f, a01 = 0.f;   // pixel p0 partials
    float s1 = 0.f, a10 = 0.f, a11 = 0.f;   // pixel p1 partials
    const float* ab0 = ab + n * 81 * HW + p0;

    for (int q = 0; q < 5; ++q) {
        const int ii = half * 5 + q;              // 0..9
        const int hbase = (y0 + ii) * HS + tx;
        const float* abr0 = ab0 + ii * 9 * HW;          // px0 tap row ii
        const float* abr1 = ab0 + 128 + (ii - 1) * 9 * HW; // px1 tap row ii-1
        const bool do0 = (ii < 9);   // px0 window rows 0..8
        const bool do1 = (ii > 0);   // px1 window rows 1..9
#pragma unroll
        for (int j = 0; j < 9; ++j) {
            const int h = hbase + j;
            const float4 A = sf[0][h], B = sf[1][h];
            const float4 C = sf[2][h], D = sf[3][h];
            const float4 R = sf[4][h];
            if (do0) {
                float dot;
                DOT16(f1r0, A, B, C, D, dot);
                float e = fmaf(-gd, R.z, fmaf(gd2, dot, c00));
                e = fmaf(gs, abr0[j * HW], e);
                const float w = __expf(e);
                s0 += w;
                a00 = fmaf(w, R.x, a00);
                a01 = fmaf(w, R.y, a01);
            }
            if (do1) {
                float dot;
                DOT16(f1r1, A, B, C, D, dot);
                float e = fmaf(-gd, R.z, fmaf(gd2, dot, c01));
                e = fmaf(gs, abr1[j * HW], e);
                const float w = __expf(e);
                s1 += w;
                a10 = fmaf(w, R.x, a10);
                a11 = fmaf(w, R.y, a11);
            }
        }
    }

    // ---- merge the two tap-halves ----
    const int tb = t & 127;
    if (half == 1) {
        part[0][tb] = s0; part[1][tb] = a00; part[2][tb] = a01;
        part[3][tb] = s1; part[4][tb] = a10; part[5][tb] = a11;
    }
    __syncthreads();
    if (half == 0) {
        s0 += part[0][tb]; a00 += part[1][tb]; a01 += part[2][tb];
        s1 += part[3][tb]; a10 += part[4][tb]; a11 += part[5][tb];
        const float i0 = 1.0f / s0, i1 = 1.0f / s1;
        outp[(n * 2 + 0) * HW + p0]       = a00 * i0;
        outp[(n * 2 + 1) * HW + p0]       = a01 * i0;
        outp[(n * 2 + 0) * HW + p0 + 128] = a10 * i1;
        outp[(n * 2 + 1) * HW + p0 + 128] = a11 * i1;
    }
}

extern "C" void kernel_launch(void* const* d_in, const int* in_sizes, int n_in,
                              void* d_out, int out_size, void* d_ws, size_t ws_size,
                              hipStream_t stream) {
    const float* delta = (const float*)d_in[0];   // [4,64,128,128]
    const float* outlo = (const float*)d_in[1];   // [4,2,64,64]
    const float* ab    = (const float*)d_in[2];   // [4,81,16384]
    const float* w1    = (const float*)d_in[3];   // [16,64]
    const float* b1    = (const float*)d_in[4];   // [16]
    const float* w2    = (const float*)d_in[5];   // [16,64]
    const float* b2    = (const float*)d_in[6];   // [16]
    const float* gd    = (const float*)d_in[7];   // scalar
    const float* gs    = (const float*)d_in[8];   // scalar
    float* outp = (float*)d_out;                  // [4,2,128,128]

    float4* f1p = (float4*)d_ws;                  // 4 MiB (4 planes x NPIX)
    float4* f2p = f1p + (size_t)4 * NPIX;         // 4 MiB
    float4* rec = f2p + (size_t)4 * NPIX;         // 1 MiB

    pass1_kernel<<<dim3(256), dim3(256), 0, stream>>>(delta, outlo, w1, b1, w2, b2,
                                                      f1p, f2p, rec);
    pass2_kernel<<<dim3(8, 8, 4), dim3(256), 0, stream>>>(f1p, f2p, rec, ab,
                                                          gd, gs, outp);
}

// Round 2
// 107.099 us; speedup vs baseline: 1.1771x; 1.1771x over previous
//
#include <hip/hip_runtime.h>

#define HGT 128
#define WID 128
#define HW  (HGT*WID)        // 16384
#define CIN 64
#define NPIX (4*HW)          // 65536 pixels total
#define TS 16                // pass2 tile side
#define HS 24                // halo side (TS + 2*4)
#define HPX (HS*HS)          // 576

// ---------------------------------------------------------------------------
// Pass 1: per-pixel 1x1 convs f1/f2 (16 ch each), |f2|^2, bilinear upsample.
// Weights staged in LDS transposed [c][32], wave-uniform reads -> broadcast.
// ---------------------------------------------------------------------------
__global__ __launch_bounds__(256) void pass1_kernel(
    const float* __restrict__ delta, const float* __restrict__ outlo,
    const float* __restrict__ w1, const float* __restrict__ b1,
    const float* __restrict__ w2, const float* __restrict__ b2,
    float4* __restrict__ f1p, float4* __restrict__ f2p, float4* __restrict__ rec)
{
    __shared__ float wlds[64][32];   // [c][o]; o<16 -> w1[o], o>=16 -> w2[o-16]
    {
        const int t = threadIdx.x;
#pragma unroll
        for (int s = 0; s < 8; ++s) {
            const int idx = t + s * 256;          // 0..2047
            const int c = idx >> 5, o = idx & 31;
            wlds[c][o] = (o < 16) ? w1[o * 64 + c] : w2[(o - 16) * 64 + c];
        }
    }
    __syncthreads();

    const int g = blockIdx.x * 256 + threadIdx.x;   // 0..65535
    const int n = g >> 14;
    const int p = g & (HW - 1);

    float f1a[16], f2a[16];
#pragma unroll
    for (int o = 0; o < 16; ++o) { f1a[o] = b1[o]; f2a[o] = b2[o]; }

    const float* dbase = delta + n * CIN * HW + p;
#pragma unroll 8
    for (int c = 0; c < CIN; ++c) {
        const float d = dbase[c * HW];
        const float4* wr = (const float4*)(&wlds[c][0]);  // uniform -> broadcast
#pragma unroll
        for (int k = 0; k < 4; ++k) {
            const float4 wv = wr[k];
            f1a[4*k+0] = fmaf(wv.x, d, f1a[4*k+0]);
            f1a[4*k+1] = fmaf(wv.y, d, f1a[4*k+1]);
            f1a[4*k+2] = fmaf(wv.z, d, f1a[4*k+2]);
            f1a[4*k+3] = fmaf(wv.w, d, f1a[4*k+3]);
        }
#pragma unroll
        for (int k = 0; k < 4; ++k) {
            const float4 wv = wr[4 + k];
            f2a[4*k+0] = fmaf(wv.x, d, f2a[4*k+0]);
            f2a[4*k+1] = fmaf(wv.y, d, f2a[4*k+1]);
            f2a[4*k+2] = fmaf(wv.z, d, f2a[4*k+2]);
            f2a[4*k+3] = fmaf(wv.w, d, f2a[4*k+3]);
        }
    }

    float f2sq = 0.f;
#pragma unroll
    for (int o = 0; o < 16; ++o) f2sq = fmaf(f2a[o], f2a[o], f2sq);

#pragma unroll
    for (int k = 0; k < 4; ++k) {
        f1p[k * NPIX + g] = make_float4(f1a[4*k], f1a[4*k+1], f1a[4*k+2], f1a[4*k+3]);
        f2p[k * NPIX + g] = make_float4(f2a[4*k], f2a[4*k+1], f2a[4*k+2], f2a[4*k+3]);
    }

    // bilinear align_corners upsample of out [N,2,64,64] at (y,x)
    const int y = p >> 7, x = p & 127;
    const float ys = (float)(y * 63) / 127.0f;
    const float xs = (float)(x * 63) / 127.0f;
    const int iy0 = (int)ys, ix0 = (int)xs;
    const float fy = ys - (float)iy0, fx = xs - (float)ix0;
    const int iy1 = min(iy0 + 1, 63), ix1 = min(ix0 + 1, 63);
    const float* ob = outlo + n * 2 * 4096;
    float o01[2];
#pragma unroll
    for (int cc = 0; cc < 2; ++cc) {
        const float* oc = ob + cc * 4096;
        const float v00 = oc[iy0*64+ix0], v01 = oc[iy0*64+ix1];
        const float v10 = oc[iy1*64+ix0], v11 = oc[iy1*64+ix1];
        const float top = v00 + fx * (v01 - v00);
        const float bot = v10 + fx * (v11 - v10);
        o01[cc] = top + fy * (bot - top);
    }
    rec[g] = make_float4(o01[0], o01[1], f2sq, 0.f);
}

// 16-FMA dot of the register f1 fragment against one halo pixel's 4 f2 planes.
#define DOT16(fr, A, B, C, D, out)                                             \
    {                                                                          \
        float d0 = fr[0]*A.x, d1 = fr[1]*A.y, d2 = fr[2]*A.z, d3 = fr[3]*A.w;  \
        d0 = fmaf(fr[ 4], B.x, d0); d1 = fmaf(fr[ 5], B.y, d1);                \
        d2 = fmaf(fr[ 6], B.z, d2); d3 = fmaf(fr[ 7], B.w, d3);                \
        d0 = fmaf(fr[ 8], C.x, d0); d1 = fmaf(fr[ 9], C.y, d1);                \
        d2 = fmaf(fr[10], C.z, d2); d3 = fmaf(fr[11], C.w, d3);                \
        d0 = fmaf(fr[12], D.x, d0); d1 = fmaf(fr[13], D.y, d1);                \
        d2 = fmaf(fr[14], D.z, d2); d3 = fmaf(fr[15], D.w, d3);                \
        out = (d0 + d1) + (d2 + d3);                                           \
    }

// One tap: halo index h, ab value av -> accumulate (s_, a0, a1).
#define TAP(h, av)                                                             \
    {                                                                          \
        const float4 A = sf[0][h], B = sf[1][h];                               \
        const float4 C = sf[2][h], D = sf[3][h];                               \
        float dot;                                                             \
        DOT16(f1r, A, B, C, D, dot);                                           \
        const float4 R = sf[4][h];                                             \
        float e = fmaf(-gd, R.z, fmaf(gd2, dot, c0));                          \
        e = fmaf(gs, (av), e);                                                 \
        const float w = __expf(e);                                             \
        s_ += w;                                                               \
        a0 = fmaf(w, R.x, a0);                                                 \
        a1 = fmaf(w, R.y, a1);                                                 \
    }

// ---------------------------------------------------------------------------
// Pass 2, v3: occupancy-first. Round-1 counters showed pass2 at 45 us with
// VALUBusy 6.4%, HBM 8%, Occupancy 9.6% -> latency-bound at 1 wave/SIMD
// (grid 256 blocks x 4 waves = 4 waves/CU). Fix: 1024 threads/block.
// Thread t: pixel px = t&255 of the 16x16 tile, tap-quarter q = t>>8.
// Quarter q handles taps tau = q, q+4, ... (tau=80 reassigned to q3 ->
// 20/20/20/21 balance). Tap walk strength-reduced: h += 4 or 19 (carry),
// ab pointer += 4*HW -> no div/mod. All loop state wave-uniform (a wave's
// 64 lanes share one quarter). Partial (sum_w, sum_w*r0, sum_w*r1) merged
// via 9 KB LDS (linear sum merge, numerics verified in round 1).
// Occupancy: 16 waves/CU (4/SIMD, VGPR capped 128 via launch_bounds) =
// 4x the latency hiding; per-thread work drops 4x. Global traffic
// unchanged except f1 fragments read by 4 quarters (block-temporal -> L2).
// ---------------------------------------------------------------------------
__global__ __launch_bounds__(1024, 4) void pass2_kernel(
    const float4* __restrict__ f1p, const float4* __restrict__ f2p,
    const float4* __restrict__ rec, const float* __restrict__ ab,
    const float* __restrict__ gdp, const float* __restrict__ gsp,
    float* __restrict__ outp)
{
    __shared__ float4 sf[5][HPX];      // 46080 B: 4 f2 planes + (r0,r1,f2sq)
    __shared__ float part[3][3][256];  // 9216 B: quarters 1..3 partials

    const int t = threadIdx.x;         // 0..1023
    const int n = blockIdx.z;
    const int bx = blockIdx.x * TS, by = blockIdx.y * TS;

    // ---- fill halo (threads 0..575) ----
    if (t < HPX) {
        const int hy = t / 24, hx = t - hy * 24;
        int gy = by - 4 + hy; gy = gy < 0 ? -gy : (gy > 127 ? 254 - gy : gy);
        int gx = bx - 4 + hx; gx = gx < 0 ? -gx : (gx > 127 ? 254 - gx : gx);
        const int gp = n * HW + gy * 128 + gx;
        sf[0][t] = f2p[0 * NPIX + gp];
        sf[1][t] = f2p[1 * NPIX + gp];
        sf[2][t] = f2p[2 * NPIX + gp];
        sf[3][t] = f2p[3 * NPIX + gp];
        sf[4][t] = rec[gp];
    }
    __syncthreads();

    const float gd = gdp[0], gs = gsp[0];
    const int px = t & 255;            // pixel within tile
    const int q  = t >> 8;             // tap quarter 0..3 (wave-uniform)
    const int tx = px & 15, ty = px >> 4;
    const int p = (by + ty) * 128 + (bx + tx);
    const int g = n * HW + p;

    float f1r[16];
#pragma unroll
    for (int k = 0; k < 4; ++k) {
        const float4 v = f1p[k * NPIX + g];
        f1r[4*k] = v.x; f1r[4*k+1] = v.y; f1r[4*k+2] = v.z; f1r[4*k+3] = v.w;
    }
    float f1sq = 0.f;
#pragma unroll
    for (int o = 0; o < 16; ++o) f1sq = fmaf(f1r[o], f1r[o], f1sq);
    const float c0 = -gd * f1sq;
    const float gd2 = 2.0f * gd;

    float s_ = 0.f, a0 = 0.f, a1 = 0.f;

    // taps tau = q, q+4, ..., q+76 (20 iters); tau=80 handled by q3 after.
    const float* abp = ab + (size_t)n * 81 * HW + p + (size_t)q * HW;
    int jj = q;                                   // tap col j (wave-uniform)
    int h  = ty * HS + tx + q;                    // halo idx for (i=0, j=q)
#pragma unroll 2
    for (int it = 0; it < 20; ++it) {
        TAP(h, abp[0]);
        abp += 4 * HW;
        jj += 4;
        const bool carry = (jj >= 9);
        jj -= carry ? 9 : 0;
        h  += carry ? 19 : 4;                     // +4, or +HS-5 on row carry
    }
    if (q == 3) {                                 // extra tap tau=80 (i=8,j=8)
        const int h80 = (ty + 8) * HS + tx + 8;
        const float* ab80 = ab + (size_t)n * 81 * HW + p + (size_t)80 * HW;
        TAP(h80, ab80[0]);
    }

    // ---- merge quarters ----
    if (q > 0) {
        part[q - 1][0][px] = s_;
        part[q - 1][1][px] = a0;
        part[q - 1][2][px] = a1;
    }
    __syncthreads();
    if (q == 0) {
#pragma unroll
        for (int k = 0; k < 3; ++k) {
            s_ += part[k][0][px];
            a0 += part[k][1][px];
            a1 += part[k][2][px];
        }
        const float inv = 1.0f / s_;
        outp[(n * 2 + 0) * HW + p] = a0 * inv;
        outp[(n * 2 + 1) * HW + p] = a1 * inv;
    }
}

extern "C" void kernel_launch(void* const* d_in, const int* in_sizes, int n_in,
                              void* d_out, int out_size, void* d_ws, size_t ws_size,
                              hipStream_t stream) {
    const float* delta = (const float*)d_in[0];   // [4,64,128,128]
    const float* outlo = (const float*)d_in[1];   // [4,2,64,64]
    const float* ab    = (const float*)d_in[2];   // [4,81,16384]
    const float* w1    = (const float*)d_in[3];   // [16,64]
    const float* b1    = (const float*)d_in[4];   // [16]
    const float* w2    = (const float*)d_in[5];   // [16,64]
    const float* b2    = (const float*)d_in[6];   // [16]
    const float* gd    = (const float*)d_in[7];   // scalar
    const float* gs    = (const float*)d_in[8];   // scalar
    float* outp = (float*)d_out;                  // [4,2,128,128]

    float4* f1p = (float4*)d_ws;                  // 4 MiB (4 planes x NPIX)
    float4* f2p = f1p + (size_t)4 * NPIX;         // 4 MiB
    float4* rec = f2p + (size_t)4 * NPIX;         // 1 MiB

    pass1_kernel<<<dim3(256), dim3(256), 0, stream>>>(delta, outlo, w1, b1, w2, b2,
                                                      f1p, f2p, rec);
    pass2_kernel<<<dim3(8, 8, 4), dim3(1024), 0, stream>>>(f1p, f2p, rec, ab,
                                                           gd, gs, outp);
}